// Round 6
// baseline (1490.619 us; speedup 1.0000x reference)
//
#include <hip/hip_runtime.h>

typedef float  f32x4 __attribute__((ext_vector_type(4)));
typedef short  s16x8 __attribute__((ext_vector_type(8)));
typedef unsigned short u16;
typedef unsigned short u16x4 __attribute__((ext_vector_type(4)));
typedef unsigned short u16x8 __attribute__((ext_vector_type(8)));

#define MFMA __builtin_amdgcn_mfma_f32_16x16x32_bf16

#define SEQ 4096
#define DIM 1024
#define NB  4

__device__ inline u16 f2bf(float f) {
  union { float f; unsigned u; } v; v.f = f;
  unsigned r = v.u + 0x7FFFu + ((v.u >> 16) & 1u);
  return (u16)(r >> 16);
}
__device__ inline float bf2f(u16 b) {
  union { unsigned u; float f; } v; v.u = ((unsigned)b) << 16;
  return v.f;
}

// ---------- x f32 -> bf16, vectorized ----------
__global__ __launch_bounds__(256) void xcvt(const float* __restrict__ X, u16* __restrict__ X16) {
  size_t i = ((size_t)blockIdx.x * 256 + threadIdx.x) * 8;
  f32x4 a = *(const f32x4*)(X + i);
  f32x4 b = *(const f32x4*)(X + i + 4);
  u16x8 p;
  p[0] = f2bf(a[0]); p[1] = f2bf(a[1]); p[2] = f2bf(a[2]); p[3] = f2bf(a[3]);
  p[4] = f2bf(b[0]); p[5] = f2bf(b[1]); p[6] = f2bf(b[2]); p[7] = f2bf(b[3]);
  *(u16x8*)(X16 + i) = p;
}

// ---------- W [e][h] f32 -> Wt [h][e] bf16 ----------
__global__ __launch_bounds__(256) void wcvt(const float* __restrict__ W, u16* __restrict__ Wt) {
  __shared__ float tile[32][33];
  int t = threadIdx.x, tx = t & 31, ty = t >> 5;
  int e0 = blockIdx.y * 32, h0 = blockIdx.x * 32;
#pragma unroll
  for (int i = 0; i < 4; ++i)
    tile[ty + i * 8][tx] = W[(size_t)(e0 + ty + i * 8) * DIM + h0 + tx];
  __syncthreads();
#pragma unroll
  for (int i = 0; i < 4; ++i)
    Wt[(size_t)(h0 + ty + i * 8) * DIM + e0 + tx] = f2bf(tile[tx][ty + i * 8]);
}

// ---------- V [b][s][h] bf16 -> Vt [b][h][s] bf16 ----------
__global__ __launch_bounds__(256) void vtrans(const u16* __restrict__ V, u16* __restrict__ Vt) {
  __shared__ u16 tile[32][34];
  int t = threadIdx.x, tx = t & 31, ty = t >> 5;
  int b = blockIdx.z;
  int s0 = blockIdx.x * 32, h0 = blockIdx.y * 32;
  const u16* Vb = V + (size_t)b * SEQ * DIM;
  u16* Vtb = Vt + (size_t)b * DIM * SEQ;
#pragma unroll
  for (int i = 0; i < 4; ++i)
    tile[ty + i * 8][tx] = Vb[(size_t)(s0 + ty + i * 8) * DIM + h0 + tx];
  __syncthreads();
#pragma unroll
  for (int i = 0; i < 4; ++i)
    Vtb[(size_t)(h0 + ty + i * 8) * SEQ + s0 + tx] = tile[tx][ty + i * 8];
}

// ---------- GEMM: C[m][n] = X16[m][k] * Wt[n][k]^T, all bf16, f32 acc ----------
__global__ __launch_bounds__(256, 2) void gemm_xw(const u16* __restrict__ X16,
                                                  const u16* __restrict__ Wt,
                                                  u16* __restrict__ C) {
  const int K = DIM, N = DIM;
  __shared__ u16 As[128 * 40];
  __shared__ u16 Bs[128 * 40];
  int m0 = blockIdx.y * 128, n0 = blockIdx.x * 128;
  int t = threadIdx.x, lane = t & 63, w = t >> 6;
  int wr = w >> 1, wc = w & 1;
  int l16 = lane & 15, lh = lane >> 4;
  f32x4 acc[4][4] = {};
  for (int kb = 0; kb < K; kb += 32) {
    __syncthreads();
#pragma unroll
    for (int i = 0; i < 2; ++i) {
      int c = t + i * 256, row = c >> 2, cc = c & 3;
      *(u16x8*)&As[row * 40 + cc * 8] = *(const u16x8*)(X16 + (size_t)(m0 + row) * K + kb + cc * 8);
      *(u16x8*)&Bs[row * 40 + cc * 8] = *(const u16x8*)(Wt  + (size_t)(n0 + row) * K + kb + cc * 8);
    }
    __syncthreads();
    s16x8 af[4], bfr[4];
#pragma unroll
    for (int mt = 0; mt < 4; ++mt)
      af[mt] = *(const s16x8*)&As[(wr * 64 + mt * 16 + l16) * 40 + lh * 8];
#pragma unroll
    for (int nt = 0; nt < 4; ++nt)
      bfr[nt] = *(const s16x8*)&Bs[(wc * 64 + nt * 16 + l16) * 40 + lh * 8];
#pragma unroll
    for (int mt = 0; mt < 4; ++mt)
#pragma unroll
      for (int nt = 0; nt < 4; ++nt)
        acc[mt][nt] = MFMA(af[mt], bfr[nt], acc[mt][nt], 0, 0, 0);
  }
#pragma unroll
  for (int mt = 0; mt < 4; ++mt)
#pragma unroll
    for (int nt = 0; nt < 4; ++nt)
#pragma unroll
      for (int r = 0; r < 4; ++r) {
        int row = m0 + wr * 64 + mt * 16 + lh * 4 + r;
        int col = n0 + wc * 64 + nt * 16 + l16;
        C[(size_t)row * N + col] = f2bf(acc[mt][nt][r]);
      }
}

// ---------- Flash attention (causal), QB=32, KB=128, 8 waves ----------
// Sp bf16 (45.8 KB LDS total) -> 2 blocks/CU = 16 waves/CU: two independent
// barrier domains per CU hide each other's L3-latency stalls.
// Grid: 512 single-tile blocks; zigzag rank->qt for load balance; XCD pair->batch.
__global__ __launch_bounds__(512, 4) void attn(const u16* __restrict__ Q,
                                               const u16* __restrict__ Kg,
                                               const u16* __restrict__ Vt,
                                               float* __restrict__ O) {
  __shared__ u16   Sp[4][128][36];   // [d-quarter][key][q-row], bf16 partial scores
  __shared__ u16   Pl[32][136];      // [q-row][key] bf16 probabilities
  __shared__ float alpha_l[32];
  __shared__ float lsum_l[32];

  int bid = blockIdx.x;
  int xcd = bid & 7;
  int batch = xcd >> 1;                       // 2 XCDs per batch (K/V L2 locality)
  int r = bid >> 3;                           // rank within XCD, 0..63
  int rz = (r & 1) ? (63 - (r >> 1)) : (r >> 1);  // zigzag: big,small alternate
  int qt = 127 - (2 * rz + (xcd & 1));        // q-tile 0..127, balanced halves
  int q0 = qt * 32;
  int nkb = (qt >> 2) + 1;

  int t = threadIdx.x, lane = t & 63, w = t >> 6;
  int d = w >> 1, kg = w & 1;
  int l16 = lane & 15, lh = lane >> 4;
  int myrow = t >> 4, mycol = t & 15;

  const u16* Qb = Q  + (size_t)batch * SEQ * DIM;
  const u16* Kb = Kg + (size_t)batch * SEQ * DIM;
  const u16* Vb = Vt + (size_t)batch * DIM * SEQ;
  float*     Ob = O  + (size_t)batch * SEQ * DIM;

  // Q fragments resident in regs: rows q0+mt*16+l16, dims d*256 + kc*32 + lh*8
  s16x8 qf[2][8];
#pragma unroll
  for (int mt = 0; mt < 2; ++mt)
#pragma unroll
    for (int kc = 0; kc < 8; ++kc)
      qf[mt][kc] = *(const s16x8*)(Qb + (size_t)(q0 + mt * 16 + l16) * DIM + d * 256 + kc * 32 + lh * 8);

  f32x4 acc[2][8] = {};
  float m_run = -1e30f, l_run = 0.f;

  for (int kb = 0; kb < nkb; ++kb) {
    int k0 = kb * 128;
    // ---- P1: QK^T partial (d-quarter of dims, kg's 64 keys) ----
    f32x4 sf[2][4] = {};
#pragma unroll
    for (int kc = 0; kc < 8; ++kc)
#pragma unroll
      for (int nt = 0; nt < 4; ++nt) {
        s16x8 kf = *(const s16x8*)(Kb + (size_t)(k0 + kg * 64 + nt * 16 + l16) * DIM + d * 256 + kc * 32 + lh * 8);
        sf[0][nt] = MFMA(qf[0][kc], kf, sf[0][nt], 0, 0, 0);
        sf[1][nt] = MFMA(qf[1][kc], kf, sf[1][nt], 0, 0, 0);
      }
#pragma unroll
    for (int mt = 0; mt < 2; ++mt)
#pragma unroll
      for (int nt = 0; nt < 4; ++nt) {
        u16x4 pk;
#pragma unroll
        for (int rr = 0; rr < 4; ++rr) pk[rr] = f2bf(sf[mt][nt][rr]);
        *(u16x4*)&Sp[d][kg * 64 + nt * 16 + l16][mt * 16 + lh * 4] = pk;
      }
    __syncthreads();

    // ---- P2: reduce 4 bf16 partials + online softmax ----
    float s[8], p[8];
#pragma unroll
    for (int j = 0; j < 8; ++j) {
      int c = mycol + 16 * j;
      float v = bf2f(Sp[0][c][myrow]) + bf2f(Sp[1][c][myrow])
              + bf2f(Sp[2][c][myrow]) + bf2f(Sp[3][c][myrow]);
      v *= 0.03125f;                              // 1/sqrt(1024)
      s[j] = (k0 + c > q0 + myrow) ? -1e30f : v;  // causal mask
    }
    float mb = s[0];
#pragma unroll
    for (int j = 1; j < 8; ++j) mb = fmaxf(mb, s[j]);
#pragma unroll
    for (int off = 1; off < 16; off <<= 1) mb = fmaxf(mb, __shfl_xor(mb, off, 16));
    float m_new = fmaxf(m_run, mb);
    float al = __expf(m_run - m_new);
    float lb = 0.f;
#pragma unroll
    for (int j = 0; j < 8; ++j) { p[j] = __expf(s[j] - m_new); lb += p[j]; }
#pragma unroll
    for (int off = 1; off < 16; off <<= 1) lb += __shfl_xor(lb, off, 16);
    l_run = l_run * al + lb;
    m_run = m_new;
#pragma unroll
    for (int j = 0; j < 8; ++j) Pl[myrow][mycol + 16 * j] = f2bf(p[j]);
    if (mycol == 0) alpha_l[myrow] = al;
    __syncthreads();

    // ---- P3: rescale O, PV over wave's 128 h-cols ----
    float a0[4], a1[4];
#pragma unroll
    for (int rr = 0; rr < 4; ++rr) { a0[rr] = alpha_l[lh * 4 + rr]; a1[rr] = alpha_l[16 + lh * 4 + rr]; }
#pragma unroll
    for (int nt = 0; nt < 8; ++nt)
#pragma unroll
      for (int rr = 0; rr < 4; ++rr) { acc[0][nt][rr] *= a0[rr]; acc[1][nt][rr] *= a1[rr]; }
    s16x8 pf[2][4];
#pragma unroll
    for (int mt = 0; mt < 2; ++mt)
#pragma unroll
      for (int kc = 0; kc < 4; ++kc)
        pf[mt][kc] = *(const s16x8*)&Pl[mt * 16 + l16][kc * 32 + lh * 8];
#pragma unroll
    for (int kc = 0; kc < 4; ++kc)
#pragma unroll
      for (int nt = 0; nt < 8; ++nt) {
        s16x8 vf = *(const s16x8*)(Vb + (size_t)(w * 128 + nt * 16 + l16) * SEQ + k0 + kc * 32 + lh * 8);
        acc[0][nt] = MFMA(pf[0][kc], vf, acc[0][nt], 0, 0, 0);
        acc[1][nt] = MFMA(pf[1][kc], vf, acc[1][nt], 0, 0, 0);
      }
  }

  // ---- epilogue: normalize by l and store fp32 ----
  if (mycol == 0) lsum_l[myrow] = l_run;
  __syncthreads();
  float li0[4], li1[4];
#pragma unroll
  for (int rr = 0; rr < 4; ++rr) {
    li0[rr] = 1.f / lsum_l[lh * 4 + rr];
    li1[rr] = 1.f / lsum_l[16 + lh * 4 + rr];
  }
#pragma unroll
  for (int nt = 0; nt < 8; ++nt)
#pragma unroll
    for (int rr = 0; rr < 4; ++rr) {
      Ob[(size_t)(q0 + lh * 4 + rr)      * DIM + w * 128 + nt * 16 + l16] = acc[0][nt][rr] * li0[rr];
      Ob[(size_t)(q0 + 16 + lh * 4 + rr) * DIM + w * 128 + nt * 16 + l16] = acc[1][nt][rr] * li1[rr];
    }
}

extern "C" void kernel_launch(void* const* d_in, const int* in_sizes, int n_in,
                              void* d_out, int out_size, void* d_ws, size_t ws_size,
                              hipStream_t stream) {
  const float* x  = (const float*)d_in[0];
  const float* Wq = (const float*)d_in[1];
  const float* Wk = (const float*)d_in[2];
  const float* Wv = (const float*)d_in[3];
  float* out = (float*)d_out;

  u16* Wtq = (u16*)d_ws;
  u16* Wtk = Wtq + (size_t)DIM * DIM;
  u16* Wtv = Wtk + (size_t)DIM * DIM;
  u16* X16 = Wtv + (size_t)DIM * DIM;
  u16* Qb  = X16 + (size_t)NB * SEQ * DIM;
  u16* Kb  = Qb  + (size_t)NB * SEQ * DIM;
  u16* Vb  = Kb  + (size_t)NB * SEQ * DIM;
  u16* Vtb = X16;  // x16 dead after the GEMMs; reuse for V^T

  xcvt<<<dim3(8192), dim3(256), 0, stream>>>(x, X16);

  wcvt<<<dim3(32, 32), dim3(256), 0, stream>>>(Wq, Wtq);
  wcvt<<<dim3(32, 32), dim3(256), 0, stream>>>(Wk, Wtk);
  wcvt<<<dim3(32, 32), dim3(256), 0, stream>>>(Wv, Wtv);

  gemm_xw<<<dim3(8, 128), dim3(256), 0, stream>>>(X16, Wtq, Qb);
  gemm_xw<<<dim3(8, 128), dim3(256), 0, stream>>>(X16, Wtk, Kb);
  gemm_xw<<<dim3(8, 128), dim3(256), 0, stream>>>(X16, Wtv, Vb);

  vtrans<<<dim3(128, 32, 4), dim3(256), 0, stream>>>(Vb, Vtb);

  attn<<<dim3(512), dim3(512), 0, stream>>>(Qb, Kb, Vtb, out);
}

// Round 7
// 1120.395 us; speedup vs baseline: 1.3304x; 1.3304x over previous
//
#include <hip/hip_runtime.h>

typedef float  f32x4 __attribute__((ext_vector_type(4)));
typedef short  s16x8 __attribute__((ext_vector_type(8)));
typedef unsigned short u16;
typedef unsigned short u16x4 __attribute__((ext_vector_type(4)));
typedef unsigned short u16x8 __attribute__((ext_vector_type(8)));

#define MFMA __builtin_amdgcn_mfma_f32_16x16x32_bf16

#define SEQ 4096
#define DIM 1024
#define NB  4

__device__ inline u16 f2bf(float f) {
  union { float f; unsigned u; } v; v.f = f;
  unsigned r = v.u + 0x7FFFu + ((v.u >> 16) & 1u);
  return (u16)(r >> 16);
}
__device__ inline float bf2f(u16 b) {
  union { unsigned u; float f; } v; v.u = ((unsigned)b) << 16;
  return v.f;
}

// ---------- x f32 -> bf16, vectorized ----------
__global__ __launch_bounds__(256) void xcvt(const float* __restrict__ X, u16* __restrict__ X16) {
  size_t i = ((size_t)blockIdx.x * 256 + threadIdx.x) * 8;
  f32x4 a = *(const f32x4*)(X + i);
  f32x4 b = *(const f32x4*)(X + i + 4);
  u16x8 p;
  p[0] = f2bf(a[0]); p[1] = f2bf(a[1]); p[2] = f2bf(a[2]); p[3] = f2bf(a[3]);
  p[4] = f2bf(b[0]); p[5] = f2bf(b[1]); p[6] = f2bf(b[2]); p[7] = f2bf(b[3]);
  *(u16x8*)(X16 + i) = p;
}

// ---------- W [e][h] f32 -> Wt [h][e] bf16 ----------
__global__ __launch_bounds__(256) void wcvt(const float* __restrict__ W, u16* __restrict__ Wt) {
  __shared__ float tile[32][33];
  int t = threadIdx.x, tx = t & 31, ty = t >> 5;
  int e0 = blockIdx.y * 32, h0 = blockIdx.x * 32;
#pragma unroll
  for (int i = 0; i < 4; ++i)
    tile[ty + i * 8][tx] = W[(size_t)(e0 + ty + i * 8) * DIM + h0 + tx];
  __syncthreads();
#pragma unroll
  for (int i = 0; i < 4; ++i)
    Wt[(size_t)(h0 + ty + i * 8) * DIM + e0 + tx] = f2bf(tile[tx][ty + i * 8]);
}

// ---------- V [b][s][h] bf16 -> Vf fragment-major [s/32][h/16][16 h][4][8 s] ----------
__global__ __launch_bounds__(256) void vtrans(const u16* __restrict__ V, u16* __restrict__ Vf) {
  __shared__ u16 tile[32][34];
  int t = threadIdx.x, tx = t & 31, ty = t >> 5;
  int b = blockIdx.z;
  int s0 = blockIdx.x * 32, h0 = blockIdx.y * 32;
  const u16* Vb = V + (size_t)b * SEQ * DIM;
  u16* Vfb = Vf + (size_t)b * DIM * SEQ;
#pragma unroll
  for (int i = 0; i < 4; ++i)
    tile[ty + i * 8][tx] = Vb[(size_t)(s0 + ty + i * 8) * DIM + h0 + tx];
  __syncthreads();
  if (t < 128) {
    int l16 = t & 15, lh = (t >> 4) & 3, hb2 = t >> 6;
    u16x8 v;
#pragma unroll
    for (int e = 0; e < 8; ++e) v[e] = tile[lh * 8 + e][hb2 * 16 + l16];
    *(u16x8*)(Vfb + ((size_t)(s0 >> 5) * (DIM / 16) + (h0 >> 4) + hb2) * 512 + l16 * 32 + lh * 8) = v;
  }
}

// ---------- GEMM: C[m][n] = X16[m][k] * Wt[n][k]^T, all bf16, f32 acc ----------
// FRAG=1: write C fragment-major [m/16][n/32][16 m][4][8 n] (for Q,K).
// FRAG=0: row-major (for V, consumed by vtrans).
template <int FRAG>
__global__ __launch_bounds__(256, 2) void gemm_xw(const u16* __restrict__ X16,
                                                  const u16* __restrict__ Wt,
                                                  u16* __restrict__ C) {
  const int K = DIM, N = DIM;
  __shared__ u16 As[128 * 40];
  __shared__ u16 Bs[128 * 40];
  int m0 = blockIdx.y * 128, n0 = blockIdx.x * 128;
  int t = threadIdx.x, lane = t & 63, w = t >> 6;
  int wr = w >> 1, wc = w & 1;
  int l16 = lane & 15, lh = lane >> 4;
  f32x4 acc[4][4] = {};
  for (int kb = 0; kb < K; kb += 32) {
    __syncthreads();
#pragma unroll
    for (int i = 0; i < 2; ++i) {
      int c = t + i * 256, row = c >> 2, cc = c & 3;
      *(u16x8*)&As[row * 40 + cc * 8] = *(const u16x8*)(X16 + (size_t)(m0 + row) * K + kb + cc * 8);
      *(u16x8*)&Bs[row * 40 + cc * 8] = *(const u16x8*)(Wt  + (size_t)(n0 + row) * K + kb + cc * 8);
    }
    __syncthreads();
    s16x8 af[4], bfr[4];
#pragma unroll
    for (int mt = 0; mt < 4; ++mt)
      af[mt] = *(const s16x8*)&As[(wr * 64 + mt * 16 + l16) * 40 + lh * 8];
#pragma unroll
    for (int nt = 0; nt < 4; ++nt)
      bfr[nt] = *(const s16x8*)&Bs[(wc * 64 + nt * 16 + l16) * 40 + lh * 8];
#pragma unroll
    for (int mt = 0; mt < 4; ++mt)
#pragma unroll
      for (int nt = 0; nt < 4; ++nt)
        acc[mt][nt] = MFMA(af[mt], bfr[nt], acc[mt][nt], 0, 0, 0);
  }
  if (FRAG) {
    // LDS micro-bounce per wave: emit fragment-major tiles (1 KB contiguous/wave)
    __syncthreads();
    u16* patch = &As[w * 640];  // [16][40] u16, 16B-aligned rows
#pragma unroll
    for (int mt = 0; mt < 4; ++mt)
#pragma unroll
      for (int np = 0; np < 2; ++np) {
#pragma unroll
        for (int h2 = 0; h2 < 2; ++h2) {
          int nt = np * 2 + h2;
#pragma unroll
          for (int r = 0; r < 4; ++r)
            patch[(lh * 4 + r) * 40 + h2 * 16 + l16] = f2bf(acc[mt][nt][r]);
        }
        __syncthreads();
        u16x8 v = *(const u16x8*)&patch[l16 * 40 + lh * 8];
        size_t sb = (size_t)((m0 + wr * 64 + mt * 16) >> 4);
        size_t dc = (size_t)((n0 + wc * 64 + np * 32) >> 5);
        *(u16x8*)(C + (sb * (DIM / 32) + dc) * 512 + l16 * 32 + lh * 8) = v;
        __syncthreads();
      }
  } else {
#pragma unroll
    for (int mt = 0; mt < 4; ++mt)
#pragma unroll
      for (int nt = 0; nt < 4; ++nt)
#pragma unroll
        for (int r = 0; r < 4; ++r) {
          int row = m0 + wr * 64 + mt * 16 + lh * 4 + r;
          int col = n0 + wc * 64 + nt * 16 + l16;
          C[(size_t)row * N + col] = f2bf(acc[mt][nt][r]);
        }
  }
}

// ---------- Flash attention (causal), QB=32, KB=128, 8 waves ----------
// Q/K/V all fragment-major: every operand load = 1 KB contiguous per wave.
// Hybrid QK^T split: wave (d,kg) = d-quarter of dims x half of keys; bf16 Sp.
__global__ __launch_bounds__(512, 2) void attn(const u16* __restrict__ Q,
                                               const u16* __restrict__ Kg,
                                               const u16* __restrict__ Vt,
                                               float* __restrict__ O) {
  __shared__ u16   Sp[4][128][36];   // [d-quarter][key][q-row], bf16 partial scores
  __shared__ u16   Pl[32][136];      // [q-row][key] bf16 probabilities
  __shared__ float alpha_l[32];
  __shared__ float lsum_l[32];

  int bid = blockIdx.x;
  int xcd = bid & 7;
  int batch = xcd >> 1;                       // 2 XCDs per batch (K/V L2 locality)
  int r = bid >> 3;                           // rank within XCD, 0..63
  int rz = (r & 1) ? (63 - (r >> 1)) : (r >> 1);  // zigzag: big,small alternate
  int qt = 127 - (2 * rz + (xcd & 1));        // q-tile 0..127, balanced halves
  int q0 = qt * 32;
  int nkb = (qt >> 2) + 1;

  int t = threadIdx.x, lane = t & 63, w = t >> 6;
  int d = w >> 1, kg = w & 1;
  int l16 = lane & 15, lh = lane >> 4;
  int lo = l16 * 32 + lh * 8;                 // intra-tile fragment offset (u16)
  int myrow = t >> 4, mycol = t & 15;

  const u16* Qb = Q  + (size_t)batch * SEQ * DIM;
  const u16* Kb = Kg + (size_t)batch * SEQ * DIM;
  const u16* Vb = Vt + (size_t)batch * DIM * SEQ;
  float*     Ob = O  + (size_t)batch * SEQ * DIM;

  // Q fragments resident in regs (fragment-major tiles)
  s16x8 qf[2][8];
#pragma unroll
  for (int mt = 0; mt < 2; ++mt)
#pragma unroll
    for (int kc = 0; kc < 8; ++kc)
      qf[mt][kc] = *(const s16x8*)(Qb + ((size_t)(qt * 2 + mt) * 32 + d * 8 + kc) * 512 + lo);

  f32x4 acc[2][8] = {};
  float m_run = -1e30f, l_run = 0.f;

  for (int kb = 0; kb < nkb; ++kb) {
    int k0 = kb * 128;
    // ---- P1: QK^T partial (d-quarter of dims, kg's 64 keys) ----
    f32x4 sf[2][4] = {};
#pragma unroll
    for (int kc = 0; kc < 8; ++kc)
#pragma unroll
      for (int nt = 0; nt < 4; ++nt) {
        s16x8 kf = *(const s16x8*)(Kb + ((size_t)(k0 / 16 + kg * 4 + nt) * 32 + d * 8 + kc) * 512 + lo);
        sf[0][nt] = MFMA(qf[0][kc], kf, sf[0][nt], 0, 0, 0);
        sf[1][nt] = MFMA(qf[1][kc], kf, sf[1][nt], 0, 0, 0);
      }
#pragma unroll
    for (int mt = 0; mt < 2; ++mt)
#pragma unroll
      for (int nt = 0; nt < 4; ++nt) {
        u16x4 pk;
#pragma unroll
        for (int rr = 0; rr < 4; ++rr) pk[rr] = f2bf(sf[mt][nt][rr]);
        *(u16x4*)&Sp[d][kg * 64 + nt * 16 + l16][mt * 16 + lh * 4] = pk;
      }
    __syncthreads();

    // ---- P2: reduce 4 bf16 partials + online softmax ----
    float s[8], p[8];
#pragma unroll
    for (int j = 0; j < 8; ++j) {
      int c = mycol + 16 * j;
      float v = bf2f(Sp[0][c][myrow]) + bf2f(Sp[1][c][myrow])
              + bf2f(Sp[2][c][myrow]) + bf2f(Sp[3][c][myrow]);
      v *= 0.03125f;                              // 1/sqrt(1024)
      s[j] = (k0 + c > q0 + myrow) ? -1e30f : v;  // causal mask
    }
    float mb = s[0];
#pragma unroll
    for (int j = 1; j < 8; ++j) mb = fmaxf(mb, s[j]);
#pragma unroll
    for (int off = 1; off < 16; off <<= 1) mb = fmaxf(mb, __shfl_xor(mb, off, 16));
    float m_new = fmaxf(m_run, mb);
    float al = __expf(m_run - m_new);
    float lb = 0.f;
#pragma unroll
    for (int j = 0; j < 8; ++j) { p[j] = __expf(s[j] - m_new); lb += p[j]; }
#pragma unroll
    for (int off = 1; off < 16; off <<= 1) lb += __shfl_xor(lb, off, 16);
    l_run = l_run * al + lb;
    m_run = m_new;
#pragma unroll
    for (int j = 0; j < 8; ++j) Pl[myrow][mycol + 16 * j] = f2bf(p[j]);
    if (mycol == 0) alpha_l[myrow] = al;
    __syncthreads();

    // ---- P3: rescale O, PV over wave's 128 h-cols (fragment-major V) ----
    float a0[4], a1[4];
#pragma unroll
    for (int rr = 0; rr < 4; ++rr) { a0[rr] = alpha_l[lh * 4 + rr]; a1[rr] = alpha_l[16 + lh * 4 + rr]; }
#pragma unroll
    for (int nt = 0; nt < 8; ++nt)
#pragma unroll
      for (int rr = 0; rr < 4; ++rr) { acc[0][nt][rr] *= a0[rr]; acc[1][nt][rr] *= a1[rr]; }
    s16x8 pf[2][4];
#pragma unroll
    for (int mt = 0; mt < 2; ++mt)
#pragma unroll
      for (int kc = 0; kc < 4; ++kc)
        pf[mt][kc] = *(const s16x8*)&Pl[mt * 16 + l16][kc * 32 + lh * 8];
#pragma unroll
    for (int kc = 0; kc < 4; ++kc)
#pragma unroll
      for (int nt = 0; nt < 8; ++nt) {
        s16x8 vf = *(const s16x8*)(Vb + ((size_t)(k0 / 32 + kc) * (DIM / 16) + w * 8 + nt) * 512 + lo);
        acc[0][nt] = MFMA(pf[0][kc], vf, acc[0][nt], 0, 0, 0);
        acc[1][nt] = MFMA(pf[1][kc], vf, acc[1][nt], 0, 0, 0);
      }
  }

  // ---- epilogue: normalize by l and store fp32 ----
  if (mycol == 0) lsum_l[myrow] = l_run;
  __syncthreads();
  float li0[4], li1[4];
#pragma unroll
  for (int rr = 0; rr < 4; ++rr) {
    li0[rr] = 1.f / lsum_l[lh * 4 + rr];
    li1[rr] = 1.f / lsum_l[16 + lh * 4 + rr];
  }
#pragma unroll
  for (int nt = 0; nt < 8; ++nt)
#pragma unroll
    for (int rr = 0; rr < 4; ++rr) {
      Ob[(size_t)(q0 + lh * 4 + rr)      * DIM + w * 128 + nt * 16 + l16] = acc[0][nt][rr] * li0[rr];
      Ob[(size_t)(q0 + 16 + lh * 4 + rr) * DIM + w * 128 + nt * 16 + l16] = acc[1][nt][rr] * li1[rr];
    }
}

extern "C" void kernel_launch(void* const* d_in, const int* in_sizes, int n_in,
                              void* d_out, int out_size, void* d_ws, size_t ws_size,
                              hipStream_t stream) {
  const float* x  = (const float*)d_in[0];
  const float* Wq = (const float*)d_in[1];
  const float* Wk = (const float*)d_in[2];
  const float* Wv = (const float*)d_in[3];
  float* out = (float*)d_out;

  u16* Wtq = (u16*)d_ws;
  u16* Wtk = Wtq + (size_t)DIM * DIM;
  u16* Wtv = Wtk + (size_t)DIM * DIM;
  u16* X16 = Wtv + (size_t)DIM * DIM;
  u16* Qb  = X16 + (size_t)NB * SEQ * DIM;
  u16* Kb  = Qb  + (size_t)NB * SEQ * DIM;
  u16* Vb  = Kb  + (size_t)NB * SEQ * DIM;
  u16* Vtb = X16;  // x16 dead after the GEMMs; reuse for fragment-major V

  xcvt<<<dim3(8192), dim3(256), 0, stream>>>(x, X16);

  wcvt<<<dim3(32, 32), dim3(256), 0, stream>>>(Wq, Wtq);
  wcvt<<<dim3(32, 32), dim3(256), 0, stream>>>(Wk, Wtk);
  wcvt<<<dim3(32, 32), dim3(256), 0, stream>>>(Wv, Wtv);

  gemm_xw<1><<<dim3(8, 128), dim3(256), 0, stream>>>(X16, Wtq, Qb);
  gemm_xw<1><<<dim3(8, 128), dim3(256), 0, stream>>>(X16, Wtk, Kb);
  gemm_xw<0><<<dim3(8, 128), dim3(256), 0, stream>>>(X16, Wtv, Vb);

  vtrans<<<dim3(128, 32, 4), dim3(256), 0, stream>>>(Vb, Vtb);

  attn<<<dim3(512), dim3(512), 0, stream>>>(Qb, Kb, Vtb, out);
}

// Round 8
// 670.788 us; speedup vs baseline: 2.2222x; 1.6703x over previous
//
#include <hip/hip_runtime.h>

typedef float  f32x4 __attribute__((ext_vector_type(4)));
typedef short  s16x8 __attribute__((ext_vector_type(8)));
typedef unsigned short u16;
typedef unsigned short u16x4 __attribute__((ext_vector_type(4)));
typedef unsigned short u16x8 __attribute__((ext_vector_type(8)));

#define MFMA __builtin_amdgcn_mfma_f32_16x16x32_bf16

#define SEQ 4096
#define DIM 1024
#define NB  4

__device__ inline u16 f2bf(float f) {
  union { float f; unsigned u; } v; v.f = f;
  unsigned r = v.u + 0x7FFFu + ((v.u >> 16) & 1u);
  return (u16)(r >> 16);
}
__device__ inline float bf2f(u16 b) {
  union { unsigned u; float f; } v; v.u = ((unsigned)b) << 16;
  return v.f;
}

// ---------- x f32 -> bf16, vectorized ----------
__global__ __launch_bounds__(256) void xcvt(const float* __restrict__ X, u16* __restrict__ X16) {
  size_t i = ((size_t)blockIdx.x * 256 + threadIdx.x) * 8;
  f32x4 a = *(const f32x4*)(X + i);
  f32x4 b = *(const f32x4*)(X + i + 4);
  u16x8 p;
  p[0] = f2bf(a[0]); p[1] = f2bf(a[1]); p[2] = f2bf(a[2]); p[3] = f2bf(a[3]);
  p[4] = f2bf(b[0]); p[5] = f2bf(b[1]); p[6] = f2bf(b[2]); p[7] = f2bf(b[3]);
  *(u16x8*)(X16 + i) = p;
}

// ---------- W [e][h] f32 -> Wt [h][e] bf16 ----------
__global__ __launch_bounds__(256) void wcvt(const float* __restrict__ W, u16* __restrict__ Wt) {
  __shared__ float tile[32][33];
  int t = threadIdx.x, tx = t & 31, ty = t >> 5;
  int e0 = blockIdx.y * 32, h0 = blockIdx.x * 32;
#pragma unroll
  for (int i = 0; i < 4; ++i)
    tile[ty + i * 8][tx] = W[(size_t)(e0 + ty + i * 8) * DIM + h0 + tx];
  __syncthreads();
#pragma unroll
  for (int i = 0; i < 4; ++i)
    Wt[(size_t)(h0 + ty + i * 8) * DIM + e0 + tx] = f2bf(tile[tx][ty + i * 8]);
}

// ---------- V [b][s][h] bf16 -> Vf fragment-major [s/32][h/16][16 h][4][8 s] ----------
__global__ __launch_bounds__(256) void vtrans(const u16* __restrict__ V, u16* __restrict__ Vf) {
  __shared__ u16 tile[32][34];
  int t = threadIdx.x, tx = t & 31, ty = t >> 5;
  int b = blockIdx.z;
  int s0 = blockIdx.x * 32, h0 = blockIdx.y * 32;
  const u16* Vb = V + (size_t)b * SEQ * DIM;
  u16* Vfb = Vf + (size_t)b * DIM * SEQ;
#pragma unroll
  for (int i = 0; i < 4; ++i)
    tile[ty + i * 8][tx] = Vb[(size_t)(s0 + ty + i * 8) * DIM + h0 + tx];
  __syncthreads();
  if (t < 128) {
    int l16 = t & 15, lh = (t >> 4) & 3, hb2 = t >> 6;
    u16x8 v;
#pragma unroll
    for (int e = 0; e < 8; ++e) v[e] = tile[lh * 8 + e][hb2 * 16 + l16];
    *(u16x8*)(Vfb + ((size_t)(s0 >> 5) * (DIM / 16) + (h0 >> 4) + hb2) * 512 + l16 * 32 + lh * 8) = v;
  }
}

// ---------- GEMM: C[m][n] = X16[m][k] * Wt[n][k]^T, all bf16, f32 acc ----------
// FRAG=1: write C fragment-major [m/16][n/32][16 m][4][8 n] (for Q,K).
// FRAG=0: row-major (for V, consumed by vtrans).
template <int FRAG>
__global__ __launch_bounds__(256, 2) void gemm_xw(const u16* __restrict__ X16,
                                                  const u16* __restrict__ Wt,
                                                  u16* __restrict__ C) {
  const int K = DIM, N = DIM;
  __shared__ u16 As[128 * 40];
  __shared__ u16 Bs[128 * 40];
  int m0 = blockIdx.y * 128, n0 = blockIdx.x * 128;
  int t = threadIdx.x, lane = t & 63, w = t >> 6;
  int wr = w >> 1, wc = w & 1;
  int l16 = lane & 15, lh = lane >> 4;
  f32x4 acc[4][4] = {};
  for (int kb = 0; kb < K; kb += 32) {
    __syncthreads();
#pragma unroll
    for (int i = 0; i < 2; ++i) {
      int c = t + i * 256, row = c >> 2, cc = c & 3;
      *(u16x8*)&As[row * 40 + cc * 8] = *(const u16x8*)(X16 + (size_t)(m0 + row) * K + kb + cc * 8);
      *(u16x8*)&Bs[row * 40 + cc * 8] = *(const u16x8*)(Wt  + (size_t)(n0 + row) * K + kb + cc * 8);
    }
    __syncthreads();
    s16x8 af[4], bfr[4];
#pragma unroll
    for (int mt = 0; mt < 4; ++mt)
      af[mt] = *(const s16x8*)&As[(wr * 64 + mt * 16 + l16) * 40 + lh * 8];
#pragma unroll
    for (int nt = 0; nt < 4; ++nt)
      bfr[nt] = *(const s16x8*)&Bs[(wc * 64 + nt * 16 + l16) * 40 + lh * 8];
#pragma unroll
    for (int mt = 0; mt < 4; ++mt)
#pragma unroll
      for (int nt = 0; nt < 4; ++nt)
        acc[mt][nt] = MFMA(af[mt], bfr[nt], acc[mt][nt], 0, 0, 0);
  }
  if (FRAG) {
    __syncthreads();
    u16* patch = &As[w * 640];  // [16][40] u16 scratch per wave
#pragma unroll
    for (int mt = 0; mt < 4; ++mt)
#pragma unroll
      for (int np = 0; np < 2; ++np) {
#pragma unroll
        for (int h2 = 0; h2 < 2; ++h2) {
          int nt = np * 2 + h2;
#pragma unroll
          for (int r = 0; r < 4; ++r)
            patch[(lh * 4 + r) * 40 + h2 * 16 + l16] = f2bf(acc[mt][nt][r]);
        }
        __syncthreads();
        u16x8 v = *(const u16x8*)&patch[l16 * 40 + lh * 8];
        size_t sb = (size_t)((m0 + wr * 64 + mt * 16) >> 4);
        size_t dc = (size_t)((n0 + wc * 64 + np * 32) >> 5);
        *(u16x8*)(C + (sb * (DIM / 32) + dc) * 512 + l16 * 32 + lh * 8) = v;
        __syncthreads();
      }
  } else {
#pragma unroll
    for (int mt = 0; mt < 4; ++mt)
#pragma unroll
      for (int nt = 0; nt < 4; ++nt)
#pragma unroll
        for (int r = 0; r < 4; ++r) {
          int row = m0 + wr * 64 + mt * 16 + lh * 4 + r;
          int col = n0 + wc * 64 + nt * 16 + l16;
          C[(size_t)row * N + col] = f2bf(acc[mt][nt][r]);
        }
  }
}

// ---------- Flash attention (causal), QB=32, KB=256, 8 waves ----------
// Fragment-major Q/K/V (1 KB contiguous per wave-load). Hybrid QK^T split:
// wave (d,kg) = d-quarter of dims x 128-key half; bf16 partial scores.
// Balance: each block serially does q-tiles {p, 127-p} -> exactly 17 steps.
// Causal skip: fully-masked 16-key (P1) / 32-key (P3) tiles are skipped.
__global__ __launch_bounds__(512, 2) void attn(const u16* __restrict__ Q,
                                               const u16* __restrict__ Kg,
                                               const u16* __restrict__ Vt,
                                               float* __restrict__ O) {
  __shared__ u16   Sp[4][256][36];   // [d-quarter][key][q-row], bf16 partials (73.7 KB)
  __shared__ u16   Pl[32][264];      // [q-row][key] bf16 probabilities (16.9 KB)
  __shared__ float alpha_l[32];
  __shared__ float lsum_l[32];

  int bid = blockIdx.x;
  int xcd = bid & 7;
  int batch = xcd >> 1;                     // 2 XCDs per batch (K/V L2 locality)
  int p = ((bid >> 3) << 1) | (xcd & 1);    // pair index 0..63 within batch

  int t = threadIdx.x, lane = t & 63, w = t >> 6;
  int d = w >> 1, kg = w & 1;
  int l16 = lane & 15, lh = lane >> 4;
  int lo = l16 * 32 + lh * 8;               // intra-tile fragment offset (u16)
  int myrow = t >> 4, mycol = t & 15;

  const u16* Qb = Q  + (size_t)batch * SEQ * DIM;
  const u16* Kb = Kg + (size_t)batch * SEQ * DIM;
  const u16* Vb = Vt + (size_t)batch * DIM * SEQ;
  float*     Ob = O  + (size_t)batch * SEQ * DIM;

  for (int tile = 0; tile < 2; ++tile) {
    int qt = tile ? (127 - p) : p;
    int q0 = qt * 32, qmax = q0 + 31;
    int nkb = (qt >> 3) + 1;

    // Q fragments resident in regs (fragment-major tiles)
    s16x8 qf[2][8];
#pragma unroll
    for (int mt = 0; mt < 2; ++mt)
#pragma unroll
      for (int kc = 0; kc < 8; ++kc)
        qf[mt][kc] = *(const s16x8*)(Qb + ((size_t)(qt * 2 + mt) * 32 + d * 8 + kc) * 512 + lo);

    f32x4 acc[2][8] = {};
    float m_run = -1e30f, l_run = 0.f;

    for (int kb = 0; kb < nkb; ++kb) {
      int k0 = kb * 256;
      // ---- P1: QK^T partial (d-quarter of dims, kg's 128 keys) ----
#pragma unroll
      for (int nt = 0; nt < 8; ++nt) {
        int kbase = k0 + kg * 128 + nt * 16;
        if (kbase <= qmax) {                 // skip fully-masked key tiles
          f32x4 s0 = {}, s1 = {};
#pragma unroll
          for (int kc = 0; kc < 8; ++kc) {
            s16x8 kf = *(const s16x8*)(Kb + ((size_t)((k0 >> 4) + kg * 8 + nt) * 32 + d * 8 + kc) * 512 + lo);
            s0 = MFMA(qf[0][kc], kf, s0, 0, 0, 0);
            s1 = MFMA(qf[1][kc], kf, s1, 0, 0, 0);
          }
          u16x4 pk0, pk1;
#pragma unroll
          for (int rr = 0; rr < 4; ++rr) { pk0[rr] = f2bf(s0[rr]); pk1[rr] = f2bf(s1[rr]); }
          *(u16x4*)&Sp[d][kg * 128 + nt * 16 + l16][lh * 4]      = pk0;
          *(u16x4*)&Sp[d][kg * 128 + nt * 16 + l16][16 + lh * 4] = pk1;
        }
      }
      __syncthreads();

      // ---- P2: reduce 4 bf16 partials + online softmax (16 keys/thread) ----
      float s[16], pp[16];
#pragma unroll
      for (int j = 0; j < 16; ++j) {
        int c = mycol + 16 * j;
        float v = bf2f(Sp[0][c][myrow]) + bf2f(Sp[1][c][myrow])
                + bf2f(Sp[2][c][myrow]) + bf2f(Sp[3][c][myrow]);
        v *= 0.03125f;                              // 1/sqrt(1024)
        s[j] = (k0 + c > q0 + myrow) ? -1e30f : v;  // causal mask
      }
      float mb = s[0];
#pragma unroll
      for (int j = 1; j < 16; ++j) mb = fmaxf(mb, s[j]);
#pragma unroll
      for (int off = 1; off < 16; off <<= 1) mb = fmaxf(mb, __shfl_xor(mb, off, 16));
      float m_new = fmaxf(m_run, mb);
      float al = __expf(m_run - m_new);
      float lb = 0.f;
#pragma unroll
      for (int j = 0; j < 16; ++j) { pp[j] = __expf(s[j] - m_new); lb += pp[j]; }
#pragma unroll
      for (int off = 1; off < 16; off <<= 1) lb += __shfl_xor(lb, off, 16);
      l_run = l_run * al + lb;
      m_run = m_new;
#pragma unroll
      for (int j = 0; j < 16; ++j) Pl[myrow][mycol + 16 * j] = f2bf(pp[j]);
      if (mycol == 0) alpha_l[myrow] = al;
      __syncthreads();

      // ---- P3: rescale O, PV over wave's 128 h-cols (fragment-major V) ----
      float a0[4], a1[4];
#pragma unroll
      for (int rr = 0; rr < 4; ++rr) { a0[rr] = alpha_l[lh * 4 + rr]; a1[rr] = alpha_l[16 + lh * 4 + rr]; }
#pragma unroll
      for (int nt = 0; nt < 8; ++nt)
#pragma unroll
        for (int rr = 0; rr < 4; ++rr) { acc[0][nt][rr] *= a0[rr]; acc[1][nt][rr] *= a1[rr]; }
#pragma unroll
      for (int kc = 0; kc < 8; ++kc) {
        if (k0 + kc * 32 <= qmax) {          // skip fully-masked key chunks
          s16x8 pf0 = *(const s16x8*)&Pl[l16][kc * 32 + lh * 8];
          s16x8 pf1 = *(const s16x8*)&Pl[16 + l16][kc * 32 + lh * 8];
#pragma unroll
          for (int nt = 0; nt < 8; ++nt) {
            s16x8 vf = *(const s16x8*)(Vb + ((size_t)((k0 >> 5) + kc) * (DIM / 16) + w * 8 + nt) * 512 + lo);
            acc[0][nt] = MFMA(pf0, vf, acc[0][nt], 0, 0, 0);
            acc[1][nt] = MFMA(pf1, vf, acc[1][nt], 0, 0, 0);
          }
        }
      }
    }

    // ---- epilogue: normalize by l and store fp32 ----
    if (mycol == 0) lsum_l[myrow] = l_run;
    __syncthreads();
    float li0[4], li1[4];
#pragma unroll
    for (int rr = 0; rr < 4; ++rr) {
      li0[rr] = 1.f / lsum_l[lh * 4 + rr];
      li1[rr] = 1.f / lsum_l[16 + lh * 4 + rr];
    }
#pragma unroll
    for (int nt = 0; nt < 8; ++nt)
#pragma unroll
      for (int rr = 0; rr < 4; ++rr) {
        Ob[(size_t)(q0 + lh * 4 + rr)      * DIM + w * 128 + nt * 16 + l16] = acc[0][nt][rr] * li0[rr];
        Ob[(size_t)(q0 + 16 + lh * 4 + rr) * DIM + w * 128 + nt * 16 + l16] = acc[1][nt][rr] * li1[rr];
      }
    __syncthreads();
  }
}

extern "C" void kernel_launch(void* const* d_in, const int* in_sizes, int n_in,
                              void* d_out, int out_size, void* d_ws, size_t ws_size,
                              hipStream_t stream) {
  const float* x  = (const float*)d_in[0];
  const float* Wq = (const float*)d_in[1];
  const float* Wk = (const float*)d_in[2];
  const float* Wv = (const float*)d_in[3];
  float* out = (float*)d_out;

  u16* Wtq = (u16*)d_ws;
  u16* Wtk = Wtq + (size_t)DIM * DIM;
  u16* Wtv = Wtk + (size_t)DIM * DIM;
  u16* X16 = Wtv + (size_t)DIM * DIM;
  u16* Qb  = X16 + (size_t)NB * SEQ * DIM;
  u16* Kb  = Qb  + (size_t)NB * SEQ * DIM;
  u16* Vb  = Kb  + (size_t)NB * SEQ * DIM;
  u16* Vtb = X16;  // x16 dead after the GEMMs; reuse for fragment-major V

  xcvt<<<dim3(8192), dim3(256), 0, stream>>>(x, X16);

  wcvt<<<dim3(32, 32), dim3(256), 0, stream>>>(Wq, Wtq);
  wcvt<<<dim3(32, 32), dim3(256), 0, stream>>>(Wk, Wtk);
  wcvt<<<dim3(32, 32), dim3(256), 0, stream>>>(Wv, Wtv);

  gemm_xw<1><<<dim3(8, 128), dim3(256), 0, stream>>>(X16, Wtq, Qb);
  gemm_xw<1><<<dim3(8, 128), dim3(256), 0, stream>>>(X16, Wtk, Kb);
  gemm_xw<0><<<dim3(8, 128), dim3(256), 0, stream>>>(X16, Wtv, Vb);

  vtrans<<<dim3(128, 32, 4), dim3(256), 0, stream>>>(Vb, Vtb);

  attn<<<dim3(256), dim3(512), 0, stream>>>(Qb, Kb, Vtb, out);
}